// Round 11
// baseline (535.431 us; speedup 1.0000x reference)
//
#include <hip/hip_runtime.h>
#include <hip/hip_bf16.h>
#include <hip/hip_fp16.h>

#define FEAT 2048
#define NCLS 751
#define NPAD 768
#define NPRB 64
#define NGAL 256
#define WSCALE 256.0f

typedef _Float16 f16x8 __attribute__((ext_vector_type(8)));
typedef float f32x4 __attribute__((ext_vector_type(4)));

__device__ __forceinline__ unsigned int f2h_u(float x) {
  union { _Float16 h; unsigned short u; } v;
  v.h = (_Float16)x;
  return (unsigned int)v.u;
}

// ---------------------------------------------------------------------------
// Kernel 1: per-feature moments -> BN scale s[f], shift t[f].  (r5 verbatim)
// ---------------------------------------------------------------------------
__global__ __launch_bounds__(256)
void stats_kernel(const float* __restrict__ P, const float* __restrict__ G,
                  const float* __restrict__ gamma, const float* __restrict__ beta,
                  float* __restrict__ st) {
  const int t = threadIdx.x;
  const int fx = t & 7, ry = t >> 3;          // 8 features x 32 row-lanes
  const int f = blockIdx.x * 8 + fx;
  float a1 = 0, a2 = 0, a3 = 0, a4 = 0;
#pragma unroll
  for (int r = ry; r < NPRB; r += 32) {       // 2 iters
    float x = P[r * FEAT + f], x2 = x * x;
    a1 += x; a2 += x2; a3 += x2 * x; a4 += x2 * x2;
  }
  float b1 = 0, b2 = 0, b3 = 0, b4 = 0;
#pragma unroll
  for (int r = ry; r < NGAL; r += 32) {       // 8 iters
    float x = G[r * FEAT + f], x2 = x * x;
    b1 += x; b2 += x2; b3 += x2 * x; b4 += x2 * x2;
  }
  __shared__ float red[8][32][8];   // [moment][ry][fx]
  __shared__ float red2[8][4][8];   // [moment][quarter][fx]
  float vals[8] = {a1, a2, a3, a4, b1, b2, b3, b4};
#pragma unroll
  for (int m = 0; m < 8; ++m) red[m][ry][fx] = vals[m];
  __syncthreads();
  {
    int m = t >> 5, q = (t >> 3) & 3, fx2 = t & 7;
    float s = 0.f;
#pragma unroll
    for (int r = 0; r < 8; ++r) s += red[m][q * 8 + r][fx2];
    red2[m][q][fx2] = s;
  }
  __syncthreads();
  if (t < 8) {
    float mm[8];
#pragma unroll
    for (int m = 0; m < 8; ++m)
      mm[m] = red2[m][0][t] + red2[m][1][t] + red2[m][2][t] + red2[m][3][t];
    float M1p = mm[0] * (1.f / NPRB), M2p = mm[1] * (1.f / NPRB);
    float M3p = mm[2] * (1.f / NPRB), M4p = mm[3] * (1.f / NPRB);
    float M1g = mm[4] * (1.f / NGAL), M2g = mm[5] * (1.f / NGAL);
    float M3g = mm[6] * (1.f / NGAL), M4g = mm[7] * (1.f / NGAL);
    float mean = M2p - 2.f * M1p * M1g + M2g;
    float Ed2 = M4p - 4.f * M3p * M1g + 6.f * M2p * M2g - 4.f * M1p * M3g + M4g;
    float var = Ed2 - mean * mean;
    int ff = blockIdx.x * 8 + t;
    float sv = gamma[ff] / sqrtf(var + 1e-5f);
    st[ff] = sv;
    st[FEAT + ff] = beta[ff] - mean * sv;  // t[f]
  }
}

// ---------------------------------------------------------------------------
// Kernel 2: Wp[c,f] = W[c,f]*s[f]*WSCALE (f16), bp[c] = b[c] + t.W  (r5 verbatim)
// ---------------------------------------------------------------------------
__global__ void prepw_kernel(const float* __restrict__ W, const float* __restrict__ b,
                             const float* __restrict__ st,
                             unsigned short* __restrict__ Wp, float* __restrict__ bp) {
  int c = blockIdx.x;
  int f = threadIdx.x * 8;
  float4 w0 = make_float4(0.f, 0.f, 0.f, 0.f), w1 = w0;
  if (c < NCLS) {
    const float4* wsrc = (const float4*)(W + (size_t)c * FEAT + f);
    w0 = wsrc[0]; w1 = wsrc[1];
  }
  const float4* s4 = (const float4*)(st + f);
  float4 s0 = s4[0], s1 = s4[1];
  const float4* t4 = (const float4*)(st + FEAT + f);
  float4 t0 = t4[0], t1 = t4[1];
  uint4 u;
  u.x = f2h_u(w0.x * s0.x * WSCALE) | (f2h_u(w0.y * s0.y * WSCALE) << 16);
  u.y = f2h_u(w0.z * s0.z * WSCALE) | (f2h_u(w0.w * s0.w * WSCALE) << 16);
  u.z = f2h_u(w1.x * s1.x * WSCALE) | (f2h_u(w1.y * s1.y * WSCALE) << 16);
  u.w = f2h_u(w1.z * s1.z * WSCALE) | (f2h_u(w1.w * s1.w * WSCALE) << 16);
  *(uint4*)(Wp + (size_t)c * FEAT + f) = u;
  float acc = t0.x * w0.x + t0.y * w0.y + t0.z * w0.z + t0.w * w0.w +
              t1.x * w1.x + t1.y * w1.y + t1.z * w1.z + t1.w * w1.w;
#pragma unroll
  for (int off = 32; off > 0; off >>= 1) acc += __shfl_down(acc, off, 64);
  __shared__ float r[4];
  int wave = threadIdx.x >> 6, lane = threadIdx.x & 63;
  if (lane == 0) r[wave] = acc;
  __syncthreads();
  if (threadIdx.x == 0) bp[c] = (c < NCLS ? b[c] : 0.f) + r[0] + r[1] + r[2] + r[3];
}

// ---------------------------------------------------------------------------
// Kernel 3 (fused GEMM): r5 main loop VERBATIM (best passing: 128x192, BK=32,
// As[cur] array indexing, 1 barrier/K-step, verified 0-conflict swizzles,
// grid (128,4)).  ONE change vs r5: staged epilogue (16-row chunks in As,
// r7-proven mechanics) -> lane-contiguous scalar out writes.
// Round-10 post-mortem: WRITE_SIZE 3.18GB == 64 iters x 48 dwords x 512thr x
// 512blk exactly => acc[4][3] spilled per-iteration. Cause: flat-smem +
// mutated LDS pointer swaps pushed peak VGPR over the (512,4) 128-reg cap.
// Reverted to r5's array-indexed form (compiles clean); epilogue staging
// reuses As storage (16x196x4 = 12.5KB <= 16KB), no new loop-carried state.
// ---------------------------------------------------------------------------
__global__ __launch_bounds__(512, 4)
void gemm_fused_kernel(const float* __restrict__ P, const float* __restrict__ G,
                       const unsigned short* __restrict__ Wp,
                       const float* __restrict__ bp, float* __restrict__ out) {
  __shared__ unsigned short As[2][128 * 32];  // 2 x 8 KB
  __shared__ unsigned short Bs[2][192 * 32];  // 2 x 12 KB

  const int tid = threadIdx.x;
  const int lane = tid & 63, wave = tid >> 6;  // 8 waves
  const int mtile = blockIdx.x, ntile = blockIdx.y;
  const int p = mtile >> 1;

  // A-gen roles: thread -> row = tid>>2 (0..127), global chunk = tid&3.
  const int arow = tid >> 2, ach = tid & 3;
  const int aoff = arow * 32 + ((ach ^ ((arow >> 1) & 3)) * 8);  // swizzled dest
  const float* gp = G + (size_t)((mtile & 1) * 128 + arow) * FEAT + ach * 8;
  const float* pp = P + (size_t)p * FEAT + ach * 8;  // L1-broadcast source

  // B staging: pre-swizzled source chunk (lane&3)^((lane>>3)&3)
  const int bch = (lane & 3) ^ ((lane >> 3) & 3);
  const unsigned short* bg0 =
      Wp + (size_t)(ntile * 192 + wave * 16 + (lane >> 2)) * FEAT + bch * 8;
  const unsigned short* bg1 =
      Wp + (size_t)(ntile * 192 + 128 + wave * 16 + (lane >> 2)) * FEAT + bch * 8;
  const int bdo0 = wave * 1024;         // dest byte offset (HW adds lane*16)
  const int bdo1 = 8192 + wave * 1024;  // second instr (wave<4 only)

  // ---- prologue: tile 0 ----
  float4 ga, gb, pa, pb;
  ga = ((const float4*)gp)[0]; gb = ((const float4*)gp)[1];
  pa = ((const float4*)pp)[0]; pb = ((const float4*)pp)[1];
  __builtin_amdgcn_global_load_lds(
      (const __attribute__((address_space(1))) void*)bg0,
      (__attribute__((address_space(3))) void*)((char*)Bs[0] + bdo0), 16, 0, 0);
  if (wave < 4)
    __builtin_amdgcn_global_load_lds(
        (const __attribute__((address_space(1))) void*)bg1,
        (__attribute__((address_space(3))) void*)((char*)Bs[0] + bdo1), 16, 0, 0);
  {  // A(0) -> As[0]
    float d0 = pa.x - ga.x, d1 = pa.y - ga.y, d2 = pa.z - ga.z, d3 = pa.w - ga.w;
    float d4 = pb.x - gb.x, d5 = pb.y - gb.y, d6 = pb.z - gb.z, d7 = pb.w - gb.w;
    uint4 u;
    u.x = f2h_u(d0 * d0) | (f2h_u(d1 * d1) << 16);
    u.y = f2h_u(d2 * d2) | (f2h_u(d3 * d3) << 16);
    u.z = f2h_u(d4 * d4) | (f2h_u(d5 * d5) << 16);
    u.w = f2h_u(d6 * d6) | (f2h_u(d7 * d7) << 16);
    *(uint4*)(As[0] + aoff) = u;
  }
  __syncthreads();  // A(0) visible; B(0) drained

  f32x4 acc[4][3];
#pragma unroll
  for (int mi = 0; mi < 4; ++mi)
#pragma unroll
    for (int ni = 0; ni < 3; ++ni) acc[mi][ni] = (f32x4){0.f, 0.f, 0.f, 0.f};

  const int wm = (wave & 1) * 64, wn = (wave >> 1) * 48;
  const int frow = lane & 15, fk = lane >> 4;
  const int fslot = fk ^ ((frow >> 1) & 3);

  // ---- main loop: 64 K-steps, one barrier each (r5 verbatim) ----
  int cur = 0;
  for (int t = 0; t < 64; ++t) {
    const int k0 = t * 32;
    const bool hn = (t < 63);

    if (hn) {
      // 1. G/P(t+1) -> regs (consumed in phase 4, under the MFMA shadow)
      const float* gn = gp + k0 + 32;
      const float* pn = pp + k0 + 32;
      ga = ((const float4*)gn)[0]; gb = ((const float4*)gn)[1];
      pa = ((const float4*)pn)[0]; pb = ((const float4*)pn)[1];
      // 2. B(t+1) -> Bs[cur^1] (drained by end-of-iteration barrier)
      __builtin_amdgcn_global_load_lds(
          (const __attribute__((address_space(1))) void*)(bg0 + k0 + 32),
          (__attribute__((address_space(3))) void*)((char*)Bs[cur ^ 1] + bdo0), 16, 0, 0);
      if (wave < 4)
        __builtin_amdgcn_global_load_lds(
            (const __attribute__((address_space(1))) void*)(bg1 + k0 + 32),
            (__attribute__((address_space(3))) void*)((char*)Bs[cur ^ 1] + bdo1), 16, 0, 0);
    }

    // 3. fragments + MFMA on buffer `cur`
    __builtin_amdgcn_s_setprio(1);
    {
      f16x8 af[4], bf[3];
#pragma unroll
      for (int mi = 0; mi < 4; ++mi)
        af[mi] = *(const f16x8*)(As[cur] + (wm + mi * 16 + frow) * 32 + fslot * 8);
#pragma unroll
      for (int ni = 0; ni < 3; ++ni)
        bf[ni] = *(const f16x8*)(Bs[cur] + (wn + ni * 16 + frow) * 32 + fslot * 8);
#pragma unroll
      for (int mi = 0; mi < 4; ++mi)
#pragma unroll
        for (int ni = 0; ni < 3; ++ni)
          acc[mi][ni] = __builtin_amdgcn_mfma_f32_16x16x32_f16(af[mi], bf[ni], acc[mi][ni], 0, 0, 0);
    }
    __builtin_amdgcn_s_setprio(0);

    // 4. A-gen(t+1) -> As[cur^1] (G/P vmcnt drains here)
    if (hn) {
      float d0 = pa.x - ga.x, d1 = pa.y - ga.y, d2 = pa.z - ga.z, d3 = pa.w - ga.w;
      float d4 = pb.x - gb.x, d5 = pb.y - gb.y, d6 = pb.z - gb.z, d7 = pb.w - gb.w;
      uint4 u;
      u.x = f2h_u(d0 * d0) | (f2h_u(d1 * d1) << 16);
      u.y = f2h_u(d2 * d2) | (f2h_u(d3 * d3) << 16);
      u.z = f2h_u(d4 * d4) | (f2h_u(d5 * d5) << 16);
      u.w = f2h_u(d6 * d6) | (f2h_u(d7 * d7) << 16);
      *(uint4*)(As[cur ^ 1] + aoff) = u;
    }

    __syncthreads();  // single drain point: B(t+1) landed, A(t+1) visible
    cur ^= 1;
  }

  // ---- staged epilogue (ONLY change vs r5): 16-row chunks via As ----
  // global row = mtile*128 + wm + mi*16 + fq*4 + r  =>  chunk c in [0,8):
  // staging waves (wave&1)==(c>>2), mi=c&3, local row = fq*4+r;
  // col = wn + ni*16 + lc.  sf = 16 x 196 f32 = 12544 B <= 16 KB (As).
  float* sf = (float*)As;
  const int LW = 196;  // stride mod 32 = 4 -> staging ~2-way max (free)
  const int fq = lane >> 4, lc = lane & 15;
#pragma unroll 1
  for (int c = 0; c < 8; ++c) {
    __syncthreads();  // sf free (main loop done / prev chunk read)
    if ((wave & 1) == (c >> 2)) {
      const int mi = c & 3;
#pragma unroll
      for (int ni = 0; ni < 3; ++ni)
#pragma unroll
        for (int r = 0; r < 4; ++r)
          sf[(fq * 4 + r) * LW + wn + ni * 16 + lc] = acc[mi][ni][r] * (1.0f / WSCALE);
    }
    __syncthreads();
    const int grow0 = mtile * 128 + c * 16;
#pragma unroll
    for (int i = 0; i < 6; ++i) {  // 16*192 elems / 512 threads
      int u = tid + i * 512;
      int row = u / 192, cin = u - row * 192;
      int col = ntile * 192 + cin;
      if (col < NCLS)
        out[(size_t)(grow0 + row) * NCLS + col] = sf[row * LW + cin] + bp[col];
    }
  }
}

// ---------------------------------------------------------------------------
extern "C" void kernel_launch(void* const* d_in, const int* in_sizes, int n_in,
                              void* d_out, int out_size, void* d_ws, size_t ws_size,
                              hipStream_t stream) {
  const float* P = (const float*)d_in[0];
  const float* G = (const float*)d_in[1];
  const float* gamma = (const float*)d_in[2];
  const float* beta = (const float*)d_in[3];
  const float* W = (const float*)d_in[4];
  const float* b = (const float*)d_in[5];
  float* out = (float*)d_out;

  float* st = (float*)d_ws;                           // s[2048], t[2048]
  float* bp = st + 2 * FEAT;                          // b'[768]
  unsigned short* Wp = (unsigned short*)(bp + NPAD);  // f16 W' [768, 2048]

  hipLaunchKernelGGL(stats_kernel, dim3(256), dim3(256), 0, stream, P, G, gamma, beta, st);
  hipLaunchKernelGGL(prepw_kernel, dim3(NPAD), dim3(256), 0, stream, W, b, st, Wp, bp);
  hipLaunchKernelGGL(gemm_fused_kernel, dim3(128, 4), dim3(512), 0, stream, P, G, Wp, bp, out);
}

// Round 12
// 161.828 us; speedup vs baseline: 3.3086x; 3.3086x over previous
//
#include <hip/hip_runtime.h>
#include <hip/hip_bf16.h>
#include <hip/hip_fp16.h>

#define FEAT 2048
#define NCLS 751
#define NPAD 768
#define NPRB 64
#define NGAL 256
#define WSCALE 256.0f

typedef _Float16 f16x8 __attribute__((ext_vector_type(8)));
typedef float f32x4 __attribute__((ext_vector_type(4)));

__device__ __forceinline__ unsigned int f2h_u(float x) {
  union { _Float16 h; unsigned short u; } v;
  v.h = (_Float16)x;
  return (unsigned int)v.u;
}

// ---------------------------------------------------------------------------
// Kernel 1: per-feature moments -> BN scale s[f], shift t[f].  (r5 verbatim)
// ---------------------------------------------------------------------------
__global__ __launch_bounds__(256)
void stats_kernel(const float* __restrict__ P, const float* __restrict__ G,
                  const float* __restrict__ gamma, const float* __restrict__ beta,
                  float* __restrict__ st) {
  const int t = threadIdx.x;
  const int fx = t & 7, ry = t >> 3;          // 8 features x 32 row-lanes
  const int f = blockIdx.x * 8 + fx;
  float a1 = 0, a2 = 0, a3 = 0, a4 = 0;
#pragma unroll
  for (int r = ry; r < NPRB; r += 32) {       // 2 iters
    float x = P[r * FEAT + f], x2 = x * x;
    a1 += x; a2 += x2; a3 += x2 * x; a4 += x2 * x2;
  }
  float b1 = 0, b2 = 0, b3 = 0, b4 = 0;
#pragma unroll
  for (int r = ry; r < NGAL; r += 32) {       // 8 iters
    float x = G[r * FEAT + f], x2 = x * x;
    b1 += x; b2 += x2; b3 += x2 * x; b4 += x2 * x2;
  }
  __shared__ float red[8][32][8];   // [moment][ry][fx]
  __shared__ float red2[8][4][8];   // [moment][quarter][fx]
  float vals[8] = {a1, a2, a3, a4, b1, b2, b3, b4};
#pragma unroll
  for (int m = 0; m < 8; ++m) red[m][ry][fx] = vals[m];
  __syncthreads();
  {
    int m = t >> 5, q = (t >> 3) & 3, fx2 = t & 7;
    float s = 0.f;
#pragma unroll
    for (int r = 0; r < 8; ++r) s += red[m][q * 8 + r][fx2];
    red2[m][q][fx2] = s;
  }
  __syncthreads();
  if (t < 8) {
    float mm[8];
#pragma unroll
    for (int m = 0; m < 8; ++m)
      mm[m] = red2[m][0][t] + red2[m][1][t] + red2[m][2][t] + red2[m][3][t];
    float M1p = mm[0] * (1.f / NPRB), M2p = mm[1] * (1.f / NPRB);
    float M3p = mm[2] * (1.f / NPRB), M4p = mm[3] * (1.f / NPRB);
    float M1g = mm[4] * (1.f / NGAL), M2g = mm[5] * (1.f / NGAL);
    float M3g = mm[6] * (1.f / NGAL), M4g = mm[7] * (1.f / NGAL);
    float mean = M2p - 2.f * M1p * M1g + M2g;
    float Ed2 = M4p - 4.f * M3p * M1g + 6.f * M2p * M2g - 4.f * M1p * M3g + M4g;
    float var = Ed2 - mean * mean;
    int ff = blockIdx.x * 8 + t;
    float sv = gamma[ff] / sqrtf(var + 1e-5f);
    st[ff] = sv;
    st[FEAT + ff] = beta[ff] - mean * sv;  // t[f]
  }
}

// ---------------------------------------------------------------------------
// Kernel 2: Wp[c,f] = W[c,f]*s[f]*WSCALE (f16), bp[c] = b[c] + t.W  (r5 verbatim)
// ---------------------------------------------------------------------------
__global__ void prepw_kernel(const float* __restrict__ W, const float* __restrict__ b,
                             const float* __restrict__ st,
                             unsigned short* __restrict__ Wp, float* __restrict__ bp) {
  int c = blockIdx.x;
  int f = threadIdx.x * 8;
  float4 w0 = make_float4(0.f, 0.f, 0.f, 0.f), w1 = w0;
  if (c < NCLS) {
    const float4* wsrc = (const float4*)(W + (size_t)c * FEAT + f);
    w0 = wsrc[0]; w1 = wsrc[1];
  }
  const float4* s4 = (const float4*)(st + f);
  float4 s0 = s4[0], s1 = s4[1];
  const float4* t4 = (const float4*)(st + FEAT + f);
  float4 t0 = t4[0], t1 = t4[1];
  uint4 u;
  u.x = f2h_u(w0.x * s0.x * WSCALE) | (f2h_u(w0.y * s0.y * WSCALE) << 16);
  u.y = f2h_u(w0.z * s0.z * WSCALE) | (f2h_u(w0.w * s0.w * WSCALE) << 16);
  u.z = f2h_u(w1.x * s1.x * WSCALE) | (f2h_u(w1.y * s1.y * WSCALE) << 16);
  u.w = f2h_u(w1.z * s1.z * WSCALE) | (f2h_u(w1.w * s1.w * WSCALE) << 16);
  *(uint4*)(Wp + (size_t)c * FEAT + f) = u;
  float acc = t0.x * w0.x + t0.y * w0.y + t0.z * w0.z + t0.w * w0.w +
              t1.x * w1.x + t1.y * w1.y + t1.z * w1.z + t1.w * w1.w;
#pragma unroll
  for (int off = 32; off > 0; off >>= 1) acc += __shfl_down(acc, off, 64);
  __shared__ float r[4];
  int wave = threadIdx.x >> 6, lane = threadIdx.x & 63;
  if (lane == 0) r[wave] = acc;
  __syncthreads();
  if (threadIdx.x == 0) bp[c] = (c < NCLS ? b[c] : 0.f) + r[0] + r[1] + r[2] + r[3];
}

// ---------------------------------------------------------------------------
// Kernel 3 (fused GEMM): r5 main loop VERBATIM + staged epilogue.
// ROUND-12 FIX: r10/r11's 3.18GB WRITE_SIZE == acc[4][3] spilled to scratch
// every K-iter (64 x 48dw x 512thr x 512blk = 3.22GB). Cause was rule #20:
// the staged epilogue indexed acc with RUNTIME mi (= c&3 under
// `#pragma unroll 1`) -> whole acc array demoted to local memory for the
// entire kernel. Fix: fully unroll the epilogue chunk loop so every
// acc[mi][ni][r] access is compile-time. (VGPR_Count CSV showed 56 in both
// spilled and clean builds -- useless for spill detection; decompose
// WRITE_SIZE instead.)
// ---------------------------------------------------------------------------
__global__ __launch_bounds__(512, 4)
void gemm_fused_kernel(const float* __restrict__ P, const float* __restrict__ G,
                       const unsigned short* __restrict__ Wp,
                       const float* __restrict__ bp, float* __restrict__ out) {
  __shared__ unsigned short As[2][128 * 32];  // 2 x 8 KB
  __shared__ unsigned short Bs[2][192 * 32];  // 2 x 12 KB

  const int tid = threadIdx.x;
  const int lane = tid & 63, wave = tid >> 6;  // 8 waves
  const int mtile = blockIdx.x, ntile = blockIdx.y;
  const int p = mtile >> 1;

  // A-gen roles: thread -> row = tid>>2 (0..127), global chunk = tid&3.
  const int arow = tid >> 2, ach = tid & 3;
  const int aoff = arow * 32 + ((ach ^ ((arow >> 1) & 3)) * 8);  // swizzled dest
  const float* gp = G + (size_t)((mtile & 1) * 128 + arow) * FEAT + ach * 8;
  const float* pp = P + (size_t)p * FEAT + ach * 8;  // L1-broadcast source

  // B staging: pre-swizzled source chunk (lane&3)^((lane>>3)&3)
  const int bch = (lane & 3) ^ ((lane >> 3) & 3);
  const unsigned short* bg0 =
      Wp + (size_t)(ntile * 192 + wave * 16 + (lane >> 2)) * FEAT + bch * 8;
  const unsigned short* bg1 =
      Wp + (size_t)(ntile * 192 + 128 + wave * 16 + (lane >> 2)) * FEAT + bch * 8;
  const int bdo0 = wave * 1024;         // dest byte offset (HW adds lane*16)
  const int bdo1 = 8192 + wave * 1024;  // second instr (wave<4 only)

  // ---- prologue: tile 0 ----
  float4 ga, gb, pa, pb;
  ga = ((const float4*)gp)[0]; gb = ((const float4*)gp)[1];
  pa = ((const float4*)pp)[0]; pb = ((const float4*)pp)[1];
  __builtin_amdgcn_global_load_lds(
      (const __attribute__((address_space(1))) void*)bg0,
      (__attribute__((address_space(3))) void*)((char*)Bs[0] + bdo0), 16, 0, 0);
  if (wave < 4)
    __builtin_amdgcn_global_load_lds(
        (const __attribute__((address_space(1))) void*)bg1,
        (__attribute__((address_space(3))) void*)((char*)Bs[0] + bdo1), 16, 0, 0);
  {  // A(0) -> As[0]
    float d0 = pa.x - ga.x, d1 = pa.y - ga.y, d2 = pa.z - ga.z, d3 = pa.w - ga.w;
    float d4 = pb.x - gb.x, d5 = pb.y - gb.y, d6 = pb.z - gb.z, d7 = pb.w - gb.w;
    uint4 u;
    u.x = f2h_u(d0 * d0) | (f2h_u(d1 * d1) << 16);
    u.y = f2h_u(d2 * d2) | (f2h_u(d3 * d3) << 16);
    u.z = f2h_u(d4 * d4) | (f2h_u(d5 * d5) << 16);
    u.w = f2h_u(d6 * d6) | (f2h_u(d7 * d7) << 16);
    *(uint4*)(As[0] + aoff) = u;
  }
  __syncthreads();  // A(0) visible; B(0) drained

  f32x4 acc[4][3];
#pragma unroll
  for (int mi = 0; mi < 4; ++mi)
#pragma unroll
    for (int ni = 0; ni < 3; ++ni) acc[mi][ni] = (f32x4){0.f, 0.f, 0.f, 0.f};

  const int wm = (wave & 1) * 64, wn = (wave >> 1) * 48;
  const int frow = lane & 15, fk = lane >> 4;
  const int fslot = fk ^ ((frow >> 1) & 3);

  // ---- main loop: 64 K-steps, one barrier each (r5 verbatim) ----
  int cur = 0;
  for (int t = 0; t < 64; ++t) {
    const int k0 = t * 32;
    const bool hn = (t < 63);

    if (hn) {
      // 1. G/P(t+1) -> regs (consumed in phase 4, under the MFMA shadow)
      const float* gn = gp + k0 + 32;
      const float* pn = pp + k0 + 32;
      ga = ((const float4*)gn)[0]; gb = ((const float4*)gn)[1];
      pa = ((const float4*)pn)[0]; pb = ((const float4*)pn)[1];
      // 2. B(t+1) -> Bs[cur^1] (drained by end-of-iteration barrier)
      __builtin_amdgcn_global_load_lds(
          (const __attribute__((address_space(1))) void*)(bg0 + k0 + 32),
          (__attribute__((address_space(3))) void*)((char*)Bs[cur ^ 1] + bdo0), 16, 0, 0);
      if (wave < 4)
        __builtin_amdgcn_global_load_lds(
            (const __attribute__((address_space(1))) void*)(bg1 + k0 + 32),
            (__attribute__((address_space(3))) void*)((char*)Bs[cur ^ 1] + bdo1), 16, 0, 0);
    }

    // 3. fragments + MFMA on buffer `cur`
    __builtin_amdgcn_s_setprio(1);
    {
      f16x8 af[4], bf[3];
#pragma unroll
      for (int mi = 0; mi < 4; ++mi)
        af[mi] = *(const f16x8*)(As[cur] + (wm + mi * 16 + frow) * 32 + fslot * 8);
#pragma unroll
      for (int ni = 0; ni < 3; ++ni)
        bf[ni] = *(const f16x8*)(Bs[cur] + (wn + ni * 16 + frow) * 32 + fslot * 8);
#pragma unroll
      for (int mi = 0; mi < 4; ++mi)
#pragma unroll
        for (int ni = 0; ni < 3; ++ni)
          acc[mi][ni] = __builtin_amdgcn_mfma_f32_16x16x32_f16(af[mi], bf[ni], acc[mi][ni], 0, 0, 0);
    }
    __builtin_amdgcn_s_setprio(0);

    // 4. A-gen(t+1) -> As[cur^1] (G/P vmcnt drains here)
    if (hn) {
      float d0 = pa.x - ga.x, d1 = pa.y - ga.y, d2 = pa.z - ga.z, d3 = pa.w - ga.w;
      float d4 = pb.x - gb.x, d5 = pb.y - gb.y, d6 = pb.z - gb.z, d7 = pb.w - gb.w;
      uint4 u;
      u.x = f2h_u(d0 * d0) | (f2h_u(d1 * d1) << 16);
      u.y = f2h_u(d2 * d2) | (f2h_u(d3 * d3) << 16);
      u.z = f2h_u(d4 * d4) | (f2h_u(d5 * d5) << 16);
      u.w = f2h_u(d6 * d6) | (f2h_u(d7 * d7) << 16);
      *(uint4*)(As[cur ^ 1] + aoff) = u;
    }

    __syncthreads();  // single drain point: B(t+1) landed, A(t+1) visible
    cur ^= 1;
  }

  // ---- staged epilogue, FULLY UNROLLED (all acc indices compile-time) ----
  // global row = mtile*128 + wm + mi*16 + fq*4 + r  =>  chunk c in [0,8):
  // staging waves (wave&1)==(c>>2), mi=c&3 (now a constant per unrolled
  // iteration), local row = fq*4+r; col = wn + ni*16 + lc.
  // sf = 16 x 196 f32 = 12544 B <= 16 KB (reuses As).
  float* sf = (float*)As;
  const int LW = 196;  // stride mod 32 = 4 -> staging ~2-way max (free)
  const int fq = lane >> 4, lc = lane & 15;
#pragma unroll
  for (int c = 0; c < 8; ++c) {
    __syncthreads();  // sf free (main loop done / prev chunk read)
    if ((wave & 1) == (c >> 2)) {
      const int mi = c & 3;  // compile-time after full unroll
#pragma unroll
      for (int ni = 0; ni < 3; ++ni)
#pragma unroll
        for (int r = 0; r < 4; ++r)
          sf[(fq * 4 + r) * LW + wn + ni * 16 + lc] = acc[mi][ni][r] * (1.0f / WSCALE);
    }
    __syncthreads();
    const int grow0 = mtile * 128 + c * 16;
#pragma unroll
    for (int i = 0; i < 6; ++i) {  // 16*192 elems / 512 threads
      int u = tid + i * 512;
      int row = u / 192, cin = u - row * 192;
      int col = ntile * 192 + cin;
      if (col < NCLS)
        out[(size_t)(grow0 + row) * NCLS + col] = sf[row * LW + cin] + bp[col];
    }
  }
}

// ---------------------------------------------------------------------------
extern "C" void kernel_launch(void* const* d_in, const int* in_sizes, int n_in,
                              void* d_out, int out_size, void* d_ws, size_t ws_size,
                              hipStream_t stream) {
  const float* P = (const float*)d_in[0];
  const float* G = (const float*)d_in[1];
  const float* gamma = (const float*)d_in[2];
  const float* beta = (const float*)d_in[3];
  const float* W = (const float*)d_in[4];
  const float* b = (const float*)d_in[5];
  float* out = (float*)d_out;

  float* st = (float*)d_ws;                           // s[2048], t[2048]
  float* bp = st + 2 * FEAT;                          // b'[768]
  unsigned short* Wp = (unsigned short*)(bp + NPAD);  // f16 W' [768, 2048]

  hipLaunchKernelGGL(stats_kernel, dim3(256), dim3(256), 0, stream, P, G, gamma, beta, st);
  hipLaunchKernelGGL(prepw_kernel, dim3(NPAD), dim3(256), 0, stream, W, b, st, Wp, bp);
  hipLaunchKernelGGL(gemm_fused_kernel, dim3(128, 4), dim3(512), 0, stream, P, G, Wp, bp, out);
}